// Round 14
// baseline (41.046 us; speedup 1.0000x reference)
//
#include <hip/hip_runtime.h>
#include <hip/hip_bf16.h>

typedef __bf16 bf8 __attribute__((ext_vector_type(8)));
typedef unsigned short u16x8 __attribute__((ext_vector_type(8)));
typedef float f32x4 __attribute__((ext_vector_type(4)));
typedef float f32x2 __attribute__((ext_vector_type(2)));
typedef unsigned int u32x4 __attribute__((ext_vector_type(4)));

union FragU { u16x8 u; bf8 b; u32x4 q; };
union BiasU { f32x4 f; u32x4 q; };

struct __attribute__((packed, aligned(4))) F4u { float v[4]; };
struct __attribute__((packed, aligned(4))) F2u { float v[2]; };

static __device__ __forceinline__ f32x4 MM(const FragU& a, const FragU& b, f32x4 c) {
  return __builtin_amdgcn_mfma_f32_16x16x32_bf16(a.b, b.b, c, 0, 0, 0);
}

#define NBATCH 524288
#define NCH 4                  // chains per wave (ILP) — R8 proved this fits spill-free
#define SPB (NCH * 16 * 4)     // samples per block-iter = 256
#define NTIL (NBATCH / SPB)    // 2048
#define GRID 512               // 2 blocks/CU resident; 4 iters/block
#define ITERS (NTIL / GRID)    // 4
#define NFRAG 37

// ============================ PREP KERNEL ============================
__global__ __launch_bounds__(64) void cdann_prep(
    const float* __restrict__ gWf1, const float* __restrict__ gbf1,
    const float* __restrict__ gWf2, const float* __restrict__ gbf2,
    const float* __restrict__ gWt1, const float* __restrict__ gbt1,
    const float* __restrict__ gWt2, const float* __restrict__ gbt2,
    const float* __restrict__ gWp1, const float* __restrict__ gbp1,
    const float* __restrict__ gWp2, const float* __restrict__ gbp2,
    const float* __restrict__ gWp3, const float* __restrict__ gbp3,
    const float* __restrict__ gWc1, const float* __restrict__ gbc1,
    const float* __restrict__ gWc2, const float* __restrict__ gbc2,
    const float* __restrict__ gWc3, const float* __restrict__ gbc3,
    u32x4* __restrict__ ws)
{
  const int lane = (int)threadIdx.x & 63;
  const int fid = (int)blockIdx.x;
  const int g = lane >> 4;
  const int c15 = lane & 15;

  auto colF2 = [](int nt, int m) -> int {
    if (nt < 2) return 8 * (m >> 2) + 4 * nt + (m & 3);
    const int gm = m >> 2, r = m & 3;
    if (gm == 0) return 32 + r;
    if (gm == 1) return 36 + r;
    if (gm == 2 && r < 2) return 40 + r;
    return -1;
  };

  if (fid >= 34) {                       // f2 bias slices (f32x4 per lane)
    const int nt = fid - 34;
    BiasU b;
#pragma unroll
    for (int r = 0; r < 4; ++r) {
      const int col = colF2(nt, g * 4 + r);
      b.f[r] = (col >= 0) ? gbf2[col] : 0.f;
    }
    ws[fid * 64 + lane] = b.q;
    return;
  }

  auto v_f1 = [&](int k, int m, int nt) -> float {
    const int n = 32 * (nt >> 1) + 8 * (m >> 2) + 4 * (nt & 1) + (m & 3);
    if (k < 30) return gWf1[k * 64 + n];
    if (k == 30) return gbf1[n];
    return 0.f;
  };
  auto v_f2 = [&](int k, int m, int nt) -> float {
    const int col = colF2(nt, m);
    return (col >= 0) ? gWf2[k * 42 + col] : 0.f;
  };
  auto ffea = [](int v) -> int {
    if (v < 36) return v;
    if (v == 36) return -2;
    if (v >= 40 && v <= 43) return v - 4;
    if (v == 48 || v == 49) return v - 8;
    return -1;
  };
  auto v_q = [&](int k, int m, int nt) -> float {
    const int i = ffea(k);
    if (i == -1) return 0.f;
    const int gm = m >> 2;
    const int u = 4 * nt + (m & 3);
    const int head = u / 5;
    const int f = 5 * gm + (u % 5);
    if (head == 0) return (i == -2) ? gbt1[f] : gWt1[i * 20 + f];
    if (head == 1) return (i == -2) ? gbp1[f] : gWp1[i * 20 + f];
    if (head == 2) return (i == -2) ? gbc1[f] : gWc1[i * 20 + f];
    return (i == -2) ? gbc1[20 + f] : gWc1[(42 + i) * 20 + f];
  };
  auto v_tp = [&](int k, int m, int nt) -> float {
    const int ks = k >> 5, j = k & 7, gk = (k >> 3) & 3;
    const int gm = m >> 2;
    const int u = 4 * nt + (m & 3);
    const int isP2 = (u < 5);
    const int cp = 5 * gm + u;
    const int isT2 = (!isP2 && gm == 0 && (u == 5 || u == 6));
    const int ct = u - 5;
    if (ks == 0) {
      if (j < 5) { const int i = 5 * gk + j; return isT2 ? gWt2[i * 2 + ct] : 0.f; }
      if (j == 7 && gk == 0) { if (isT2) return gbt2[ct]; if (isP2) return gbp2[cp]; }
      return 0.f;
    } else {
      if (j < 5) { const int i = 5 * gk + j; return isP2 ? gWp2[i * 20 + cp] : 0.f; }
      return 0.f;
    }
  };
  auto v_cc = [&](int k, int m, int nt) -> float {
    const int ks = k >> 5, j = k & 7, gk = (k >> 3) & 3;
    const int gm = m >> 2;
    const int u = 4 * nt + (m & 3);
    const int isE0 = (u < 5);
    const int isE1 = (u >= 5 && u < 10);
    const int c0 = 5 * gm + u;
    const int c1 = 5 * gm + (u - 5);
    if (ks == 0) {
      if (j < 5) { const int i = 5 * gk + j; return isE0 ? gWc2[i * 20 + c0] : 0.f; }
      if (j == 7 && gk == 0) { if (isE0) return gbc2[c0]; if (isE1) return gbc2[20 + c1]; }
      return 0.f;
    } else {
      if (j < 5) { const int i = 5 * gk + j; return isE1 ? gWc2[(20 + i) * 20 + c1] : 0.f; }
      return 0.f;
    }
  };
  auto v_o = [&](int k, int m, int nt) -> float {
    const int ks = k >> 5, j = k & 7, gk = (k >> 3) & 3;
    const int gm = m >> 2, r = m & 3;
    int kind = -1, c = 0;   // 0=pd, 1=cd0, 2=cd1
    if (nt == 0) {
      if (gm == 0) { kind = 0; c = r; }
      else if (gm == 1) { if (r < 2) { kind = 0; c = 4 + r; } else { kind = 1; c = r - 2; } }
      else if (gm == 2) { kind = 1; c = 2 + r; }
      else { kind = 2; c = r; }
    } else {
      if (gm == 0 && r < 2) { kind = 2; c = 4 + r; }
    }
    if (kind < 0) return 0.f;
    if (ks == 0) {
      if (j < 5) { const int i = 5 * gk + j; return (kind == 0) ? gWp3[i * 6 + c] : 0.f; }
      if (j < 7) { const int i = 5 * gk + (j - 5); return (kind == 2) ? gWc3[(20 + i) * 6 + c] : 0.f; }
      if (gk == 0) {
        if (kind == 0) return gbp3[c];
        if (kind == 1) return gbc3[c];
        return gbc3[6 + c];
      }
      return 0.f;
    } else {
      if (j < 5) { const int i = 5 * gk + j; return (kind == 1) ? gWc3[i * 6 + c] : 0.f; }
      const int i = 5 * gk + 2 + (j - 5);
      return (kind == 2) ? gWc3[(20 + i) * 6 + c] : 0.f;
    }
  };

  int ks, nt, which;
  if (fid < 4)       { ks = 0;                nt = fid;            which = 0; }
  else if (fid < 10) { int t = fid - 4;  ks = t / 3; nt = t % 3;   which = 1; }
  else if (fid < 20) { int t = fid - 10; ks = t / 5; nt = t % 5;   which = 2; }
  else if (fid < 24) { int t = fid - 20; ks = t / 2; nt = t % 2;   which = 3; }
  else if (fid < 30) { int t = fid - 24; ks = t / 3; nt = t % 3;   which = 4; }
  else               { int t = fid - 30; ks = t / 2; nt = t % 2;   which = 5; }

  FragU f;
#pragma unroll
  for (int j = 0; j < 8; ++j) {
    const int k = ks * 32 + g * 8 + j;
    float v;
    switch (which) {
      case 0: v = v_f1(k, c15, nt); break;
      case 1: v = v_f2(k, c15, nt); break;
      case 2: v = v_q(k, c15, nt); break;
      case 3: v = v_tp(k, c15, nt); break;
      case 4: v = v_cc(k, c15, nt); break;
      default: v = v_o(k, c15, nt); break;
    }
    f.b[j] = (__bf16)v;
  }
  ws[fid * 64 + lane] = f.q;
}

// ============================ MAIN KERNEL ============================
// R8 structure (NCH=4, all frags pinned, zero spill at VGPR=120) fixed:
// GRID=512 so all blocks are resident, plus a LOW-REGISTER staggered
// prefetch: chains 0,1 prefetched cross-iteration as bf16 frags (8 regs);
// chains 2,3 loaded at iter start and packed only after f1+f2 of chains
// 0,1 (latency hides under ~800cy of compute). Min-waves stays 2 (R5/R12:
// higher values quantize the reg budget down and spill).
__global__ __launch_bounds__(256, 2) void cdann_fwd(
    const float* __restrict__ gx, const int* __restrict__ gy,
    const u32x4* __restrict__ ws, float* __restrict__ gout)
{
  const int tid = (int)threadIdx.x;
  const int lane = tid & 63;
  const int w = tid >> 6;
  const int g = lane >> 4;
  const int c15 = lane & 15;

  // ---- prologue: 37 coalesced dwordx4 loads of prebuilt fragments ----
  FragU wF1[4], wF2[2][3], wQ[2][5], wTP[2][2], wCC[2][3], wO[2][2];
#pragma unroll
  for (int nt = 0; nt < 4; ++nt) wF1[nt].q = ws[nt * 64 + lane];
#pragma unroll
  for (int ks = 0; ks < 2; ++ks) {
#pragma unroll
    for (int nt = 0; nt < 3; ++nt) wF2[ks][nt].q = ws[(4 + ks * 3 + nt) * 64 + lane];
#pragma unroll
    for (int nt = 0; nt < 5; ++nt) wQ[ks][nt].q = ws[(10 + ks * 5 + nt) * 64 + lane];
#pragma unroll
    for (int nt = 0; nt < 2; ++nt) wTP[ks][nt].q = ws[(20 + ks * 2 + nt) * 64 + lane];
#pragma unroll
    for (int nt = 0; nt < 3; ++nt) wCC[ks][nt].q = ws[(24 + ks * 3 + nt) * 64 + lane];
#pragma unroll
    for (int nt = 0; nt < 2; ++nt) wO[ks][nt].q = ws[(30 + ks * 2 + nt) * 64 + lane];
  }
  f32x4 bF2[3];
#pragma unroll
  for (int nt = 0; nt < 3; ++nt) {
    BiasU b; b.q = ws[(34 + nt) * 64 + lane];
    bF2[nt] = b.f;
  }

  // ---- pin loop-invariants (anti-remat / anti-sink) ----
#pragma unroll
  for (int nt = 0; nt < 4; ++nt) asm volatile("" : "+v"(wF1[nt].u));
#pragma unroll
  for (int ks = 0; ks < 2; ++ks) {
#pragma unroll
    for (int nt = 0; nt < 3; ++nt) asm volatile("" : "+v"(wF2[ks][nt].u));
#pragma unroll
    for (int nt = 0; nt < 5; ++nt) asm volatile("" : "+v"(wQ[ks][nt].u));
#pragma unroll
    for (int nt = 0; nt < 2; ++nt) asm volatile("" : "+v"(wTP[ks][nt].u));
#pragma unroll
    for (int nt = 0; nt < 3; ++nt) asm volatile("" : "+v"(wCC[ks][nt].u));
#pragma unroll
    for (int nt = 0; nt < 2; ++nt) asm volatile("" : "+v"(wO[ks][nt].u));
  }
#pragma unroll
  for (int nt = 0; nt < 3; ++nt) asm volatile("" : "+v"(bF2[nt]));

  const f32x4 zf = {0.f, 0.f, 0.f, 0.f};
  const __bf16 one = (__bf16)1.0f;
  const __bf16 zero = (__bf16)0.0f;
  float* const outT = gout;
  float* const outP = gout + (size_t)2 * NBATCH;
  float* const outC = gout + (size_t)8 * NBATCH;

  // ---- cross-iter prefetch: chains 0,1 as bf16 frags (8 regs) + all y (4) ----
  FragU bxp01[2];
  int ysp[NCH];
  auto loadx01 = [&](int it) {
    const int base = it * SPB + w * (NCH * 16) + c15;
#pragma unroll
    for (int c = 0; c < 2; ++c) {
      const int s = base + c * 16;
      const float* xp = gx + (size_t)s * 30 + g * 8;
      float t[8];
      if (g < 3) {
        F4u a0 = *(const F4u*)xp; F4u a1 = *(const F4u*)(xp + 4);
#pragma unroll
        for (int j = 0; j < 4; ++j) { t[j] = a0.v[j]; t[4 + j] = a1.v[j]; }
      } else {
        F4u a0 = *(const F4u*)xp; F2u a1 = *(const F2u*)(xp + 4);
#pragma unroll
        for (int j = 0; j < 4; ++j) t[j] = a0.v[j];
        t[4] = a1.v[0]; t[5] = a1.v[1];
        t[6] = 1.0f; t[7] = 0.0f;   // k=30 const1 (bias fold), k=31 zero
      }
#pragma unroll
      for (int j = 0; j < 8; ++j) bxp01[c].b[j] = (__bf16)t[j];
    }
#pragma unroll
    for (int c = 0; c < NCH; ++c) ysp[c] = gy[base + c * 16];
  };

  loadx01((int)blockIdx.x);

  for (int ii = 0; ii < ITERS; ++ii) {
    const int it = (int)blockIdx.x + ii * GRID;
    const int base = it * SPB + w * (NCH * 16) + c15;

    // consume prefetched chains 0,1 + y
    FragU bx[NCH];
    int ysl[NCH];
    bx[0] = bxp01[0]; bx[1] = bxp01[1];
#pragma unroll
    for (int c = 0; c < NCH; ++c) ysl[c] = ysp[c];

    // issue chains 2,3 x loads NOW; packed after f1+f2 of chains 0,1
    float xr23[2][8];
#pragma unroll
    for (int c = 0; c < 2; ++c) {
      const int s = base + (2 + c) * 16;
      const float* xp = gx + (size_t)s * 30 + g * 8;
      if (g < 3) {
        F4u a0 = *(const F4u*)xp; F4u a1 = *(const F4u*)(xp + 4);
#pragma unroll
        for (int j = 0; j < 4; ++j) { xr23[c][j] = a0.v[j]; xr23[c][4 + j] = a1.v[j]; }
      } else {
        F4u a0 = *(const F4u*)xp; F2u a1 = *(const F2u*)(xp + 4);
#pragma unroll
        for (int j = 0; j < 4; ++j) xr23[c][j] = a0.v[j];
        xr23[c][4] = a1.v[0]; xr23[c][5] = a1.v[1];
        xr23[c][6] = 1.0f; xr23[c][7] = 0.0f;
      }
    }

    FragU bh0[NCH], bh1[NCH];
    FragU bf0[NCH], bf1[NCH];

    // ---- f1+f2 for chains 0,1 (covers chains 2,3 load latency) ----
#pragma unroll
    for (int c = 0; c < 2; ++c) {
      f32x4 aH[4];
#pragma unroll
      for (int nt = 0; nt < 4; ++nt) aH[nt] = MM(wF1[nt], bx[c], zf);
#pragma unroll
      for (int j = 0; j < 8; ++j) {
        bh0[c].b[j] = (__bf16)fmaxf(aH[j >> 2][j & 3], 0.f);
        bh1[c].b[j] = (__bf16)fmaxf(aH[2 + (j >> 2)][j & 3], 0.f);
      }
    }
#pragma unroll
    for (int c = 0; c < 2; ++c) {
      f32x4 aF[3];
#pragma unroll
      for (int nt = 0; nt < 3; ++nt) aF[nt] = MM(wF2[1][nt], bh1[c], MM(wF2[0][nt], bh0[c], zf));
#pragma unroll
      for (int j = 0; j < 8; ++j)
        bf0[c].b[j] = (__bf16)fmaxf(aF[j >> 2][j & 3] + bF2[j >> 2][j & 3], 0.f);
#pragma unroll
      for (int j = 0; j < 4; ++j)
        bf1[c].b[j] = (__bf16)fmaxf(aF[2][j] + bF2[2][j], 0.f);
      bf1[c].b[4] = (g == 0) ? one : zero;
      bf1[c].b[5] = zero; bf1[c].b[6] = zero; bf1[c].b[7] = zero;
    }

    // pack chains 2,3 (loads have landed under f1/f2 of 0,1)
#pragma unroll
    for (int c = 0; c < 2; ++c)
#pragma unroll
      for (int j = 0; j < 8; ++j) bx[2 + c].b[j] = (__bf16)xr23[c][j];

    // next iter's chain-0/1 + y prefetch flies under the rest of this iter
    if (ii + 1 < ITERS) loadx01(it + GRID);

    // ---- f1+f2 for chains 2,3 ----
#pragma unroll
    for (int c = 2; c < 4; ++c) {
      f32x4 aH[4];
#pragma unroll
      for (int nt = 0; nt < 4; ++nt) aH[nt] = MM(wF1[nt], bx[c], zf);
#pragma unroll
      for (int j = 0; j < 8; ++j) {
        bh0[c].b[j] = (__bf16)fmaxf(aH[j >> 2][j & 3], 0.f);
        bh1[c].b[j] = (__bf16)fmaxf(aH[2 + (j >> 2)][j & 3], 0.f);
      }
    }
#pragma unroll
    for (int c = 2; c < 4; ++c) {
      f32x4 aF[3];
#pragma unroll
      for (int nt = 0; nt < 3; ++nt) aF[nt] = MM(wF2[1][nt], bh1[c], MM(wF2[0][nt], bh0[c], zf));
#pragma unroll
      for (int j = 0; j < 8; ++j)
        bf0[c].b[j] = (__bf16)fmaxf(aF[j >> 2][j & 3] + bF2[j >> 2][j & 3], 0.f);
#pragma unroll
      for (int j = 0; j < 4; ++j)
        bf1[c].b[j] = (__bf16)fmaxf(aF[2][j] + bF2[2][j], 0.f);
      bf1[c].b[4] = (g == 0) ? one : zero;
      bf1[c].b[5] = zero; bf1[c].b[6] = zero; bf1[c].b[7] = zero;
    }

    // ---- stages 3-5 fused per chain (quad -> heads -> out), results kept ----
    f32x4 aOr0[NCH], aOr1[NCH];
    f32x2 t2v[NCH];
#pragma unroll
    for (int c = 0; c < NCH; ++c) {
      f32x4 aQ[5];
#pragma unroll
      for (int nt = 0; nt < 5; ++nt) aQ[nt] = MM(wQ[1][nt], bf1[c], MM(wQ[0][nt], bf0[c], zf));
      auto rq = [&](int u) { return (__bf16)fmaxf(aQ[u >> 2][u & 3], 0.f); };
      FragU tp0, tp1, cc0, cc1;
#pragma unroll
      for (int j = 0; j < 5; ++j) {
        tp0.b[j] = rq(j);
        tp1.b[j] = rq(5 + j);
        cc0.b[j] = rq(10 + j);
        cc1.b[j] = rq(15 + j);
      }
      tp0.b[5] = zero; tp0.b[6] = zero; tp0.b[7] = (g == 0) ? one : zero;
      tp1.b[5] = zero; tp1.b[6] = zero; tp1.b[7] = zero;
      cc0.b[5] = zero; cc0.b[6] = zero; cc0.b[7] = (g == 0) ? one : zero;
      cc1.b[5] = zero; cc1.b[6] = zero; cc1.b[7] = zero;
      f32x4 aT[2], aC[3];
#pragma unroll
      for (int nt = 0; nt < 2; ++nt) aT[nt] = MM(wTP[1][nt], tp1, MM(wTP[0][nt], tp0, zf));
#pragma unroll
      for (int nt = 0; nt < 3; ++nt) aC[nt] = MM(wCC[1][nt], cc1, MM(wCC[0][nt], cc0, zf));
      FragU f50, f51;
#pragma unroll
      for (int j = 0; j < 4; ++j) {
        f50.b[j] = (__bf16)fmaxf(aT[0][j], 0.f);
        f51.b[j] = (__bf16)fmaxf(aC[0][j], 0.f);
      }
      f50.b[4] = (__bf16)fmaxf(aT[1][0], 0.f);
      f50.b[5] = (__bf16)fmaxf(aC[1][1], 0.f);
      f50.b[6] = (__bf16)fmaxf(aC[1][2], 0.f);
      f50.b[7] = (g == 0) ? one : zero;
      f51.b[4] = (__bf16)fmaxf(aC[1][0], 0.f);
      f51.b[5] = (__bf16)fmaxf(aC[1][3], 0.f);
      f51.b[6] = (__bf16)fmaxf(aC[2][0], 0.f);
      f51.b[7] = (__bf16)fmaxf(aC[2][1], 0.f);
      aOr0[c] = MM(wO[0][0], f50, zf);
      aOr0[c] = MM(wO[1][0], f51, aOr0[c]);
      aOr1[c] = MM(wO[0][1], f50, zf);
      aOr1[c] = MM(wO[1][1], f51, aOr1[c]);
      t2v[c][0] = aT[1][1]; t2v[c][1] = aT[1][2];
    }

    // ---- stores (branches isolated at tail) ----
#pragma unroll
    for (int c = 0; c < NCH; ++c) {
      const int s = base + c * 16;
      const int y = ysl[c];
      const f32x4 aO0 = aOr0[c], aO1 = aOr1[c];
      if (g == 0) {
        *(f32x2*)(outT + (size_t)s * 2) = t2v[c];
        f32x2 pa = {aO0[0], aO0[1]}, pb = {aO0[2], aO0[3]};
        *(f32x2*)(outP + (size_t)s * 6) = pa;
        *(f32x2*)(outP + (size_t)s * 6 + 2) = pb;
        if (y) { f32x2 cv = {aO1[0], aO1[1]}; *(f32x2*)(outC + (size_t)s * 6 + 4) = cv; }
      } else if (g == 1) {
        f32x2 pc = {aO0[0], aO0[1]};
        *(f32x2*)(outP + (size_t)s * 6 + 4) = pc;
        if (!y) { f32x2 cv = {aO0[2], aO0[3]}; *(f32x2*)(outC + (size_t)s * 6) = cv; }
      } else if (g == 2) {
        if (!y) {
          f32x2 ca = {aO0[0], aO0[1]}, cb = {aO0[2], aO0[3]};
          *(f32x2*)(outC + (size_t)s * 6 + 2) = ca;
          *(f32x2*)(outC + (size_t)s * 6 + 4) = cb;
        }
      } else {
        if (y) {
          f32x2 ca = {aO0[0], aO0[1]}, cb = {aO0[2], aO0[3]};
          *(f32x2*)(outC + (size_t)s * 6) = ca;
          *(f32x2*)(outC + (size_t)s * 6 + 2) = cb;
        }
      }
    }
  }
}

extern "C" void kernel_launch(void* const* d_in, const int* in_sizes, int n_in,
                              void* d_out, int out_size, void* d_ws, size_t ws_size,
                              hipStream_t stream) {
  (void)in_sizes; (void)n_in; (void)ws_size; (void)out_size;
  const float* gx  = (const float*)d_in[0];
  const int*   gy  = (const int*)d_in[1];
  const float* Wf1 = (const float*)d_in[2];  const float* bf1 = (const float*)d_in[3];
  const float* Wf2 = (const float*)d_in[4];  const float* bf2 = (const float*)d_in[5];
  const float* Wt1 = (const float*)d_in[6];  const float* bt1 = (const float*)d_in[7];
  const float* Wt2 = (const float*)d_in[8];  const float* bt2 = (const float*)d_in[9];
  const float* Wp1 = (const float*)d_in[10]; const float* bp1 = (const float*)d_in[11];
  const float* Wp2 = (const float*)d_in[12]; const float* bp2 = (const float*)d_in[13];
  const float* Wp3 = (const float*)d_in[14]; const float* bp3 = (const float*)d_in[15];
  const float* Wc1 = (const float*)d_in[16]; const float* bc1 = (const float*)d_in[17];
  const float* Wc2 = (const float*)d_in[18]; const float* bc2 = (const float*)d_in[19];
  const float* Wc3 = (const float*)d_in[20]; const float* bc3 = (const float*)d_in[21];
  float* out = (float*)d_out;
  u32x4* ws = (u32x4*)d_ws;

  cdann_prep<<<dim3(NFRAG), dim3(64), 0, stream>>>(
      Wf1, bf1, Wf2, bf2, Wt1, bt1, Wt2, bt2,
      Wp1, bp1, Wp2, bp2, Wp3, bp3, Wc1, bc1, Wc2, bc2, Wc3, bc3, ws);

  cdann_fwd<<<dim3(GRID), dim3(256), 0, stream>>>(gx, gy, ws, out);
}

// Round 15
// 36.100 us; speedup vs baseline: 1.1370x; 1.1370x over previous
//
#include <hip/hip_runtime.h>
#include <hip/hip_bf16.h>

typedef __bf16 bf8 __attribute__((ext_vector_type(8)));
typedef unsigned short u16x8 __attribute__((ext_vector_type(8)));
typedef float f32x4 __attribute__((ext_vector_type(4)));
typedef float f32x2 __attribute__((ext_vector_type(2)));
typedef unsigned int u32x4 __attribute__((ext_vector_type(4)));

union FragU { u16x8 u; bf8 b; u32x4 q; };
union BiasU { f32x4 f; u32x4 q; };

struct __attribute__((packed, aligned(4))) F4u { float v[4]; };
struct __attribute__((packed, aligned(4))) F2u { float v[2]; };

static __device__ __forceinline__ f32x4 MM(const FragU& a, const FragU& b, f32x4 c) {
  return __builtin_amdgcn_mfma_f32_16x16x32_bf16(a.b, b.b, c, 0, 0, 0);
}

#define NBATCH 524288
#define NTIL (NBATCH / 128)   // 128 samples per block-iteration (2 chains x 64)
#define GRID 512              // 2 blocks/CU (reg-capped at 2 waves/SIMD)
#define NFRAG 37              // 34 weight frags + 3 f2-bias slices

// ============================ PREP KERNEL ============================
// One wave per fragment: builds the permuted-layout A-fragment and stores
// 16 B/lane into ws[fid*64 + lane]. Removes ~300 branchy per-lane gathers
// from every main-kernel wave (R7: 45.1 -> 36.3 us).
__global__ __launch_bounds__(64) void cdann_prep(
    const float* __restrict__ gWf1, const float* __restrict__ gbf1,
    const float* __restrict__ gWf2, const float* __restrict__ gbf2,
    const float* __restrict__ gWt1, const float* __restrict__ gbt1,
    const float* __restrict__ gWt2, const float* __restrict__ gbt2,
    const float* __restrict__ gWp1, const float* __restrict__ gbp1,
    const float* __restrict__ gWp2, const float* __restrict__ gbp2,
    const float* __restrict__ gWp3, const float* __restrict__ gbp3,
    const float* __restrict__ gWc1, const float* __restrict__ gbc1,
    const float* __restrict__ gWc2, const float* __restrict__ gbc2,
    const float* __restrict__ gWc3, const float* __restrict__ gbc3,
    u32x4* __restrict__ ws)
{
  const int lane = (int)threadIdx.x & 63;
  const int fid = (int)blockIdx.x;
  const int g = lane >> 4;
  const int c15 = lane & 15;

  auto colF2 = [](int nt, int m) -> int {
    if (nt < 2) return 8 * (m >> 2) + 4 * nt + (m & 3);
    const int gm = m >> 2, r = m & 3;
    if (gm == 0) return 32 + r;
    if (gm == 1) return 36 + r;
    if (gm == 2 && r < 2) return 40 + r;
    return -1;
  };

  if (fid >= 34) {                       // f2 bias slices (f32x4 per lane)
    const int nt = fid - 34;
    BiasU b;
#pragma unroll
    for (int r = 0; r < 4; ++r) {
      const int col = colF2(nt, g * 4 + r);
      b.f[r] = (col >= 0) ? gbf2[col] : 0.f;
    }
    ws[fid * 64 + lane] = b.q;
    return;
  }

  auto v_f1 = [&](int k, int m, int nt) -> float {
    const int n = 32 * (nt >> 1) + 8 * (m >> 2) + 4 * (nt & 1) + (m & 3);
    if (k < 30) return gWf1[k * 64 + n];
    if (k == 30) return gbf1[n];
    return 0.f;
  };
  auto v_f2 = [&](int k, int m, int nt) -> float {
    const int col = colF2(nt, m);
    return (col >= 0) ? gWf2[k * 42 + col] : 0.f;
  };
  auto ffea = [](int v) -> int {
    if (v < 36) return v;
    if (v == 36) return -2;
    if (v >= 40 && v <= 43) return v - 4;
    if (v == 48 || v == 49) return v - 8;
    return -1;
  };
  auto v_q = [&](int k, int m, int nt) -> float {
    const int i = ffea(k);
    if (i == -1) return 0.f;
    const int gm = m >> 2;
    const int u = 4 * nt + (m & 3);
    const int head = u / 5;
    const int f = 5 * gm + (u % 5);
    if (head == 0) return (i == -2) ? gbt1[f] : gWt1[i * 20 + f];
    if (head == 1) return (i == -2) ? gbp1[f] : gWp1[i * 20 + f];
    if (head == 2) return (i == -2) ? gbc1[f] : gWc1[i * 20 + f];
    return (i == -2) ? gbc1[20 + f] : gWc1[(42 + i) * 20 + f];
  };
  auto v_tp = [&](int k, int m, int nt) -> float {
    const int ks = k >> 5, j = k & 7, gk = (k >> 3) & 3;
    const int gm = m >> 2;
    const int u = 4 * nt + (m & 3);
    const int isP2 = (u < 5);
    const int cp = 5 * gm + u;
    const int isT2 = (!isP2 && gm == 0 && (u == 5 || u == 6));
    const int ct = u - 5;
    if (ks == 0) {
      if (j < 5) { const int i = 5 * gk + j; return isT2 ? gWt2[i * 2 + ct] : 0.f; }
      if (j == 7 && gk == 0) { if (isT2) return gbt2[ct]; if (isP2) return gbp2[cp]; }
      return 0.f;
    } else {
      if (j < 5) { const int i = 5 * gk + j; return isP2 ? gWp2[i * 20 + cp] : 0.f; }
      return 0.f;
    }
  };
  auto v_cc = [&](int k, int m, int nt) -> float {
    const int ks = k >> 5, j = k & 7, gk = (k >> 3) & 3;
    const int gm = m >> 2;
    const int u = 4 * nt + (m & 3);
    const int isE0 = (u < 5);
    const int isE1 = (u >= 5 && u < 10);
    const int c0 = 5 * gm + u;
    const int c1 = 5 * gm + (u - 5);
    if (ks == 0) {
      if (j < 5) { const int i = 5 * gk + j; return isE0 ? gWc2[i * 20 + c0] : 0.f; }
      if (j == 7 && gk == 0) { if (isE0) return gbc2[c0]; if (isE1) return gbc2[20 + c1]; }
      return 0.f;
    } else {
      if (j < 5) { const int i = 5 * gk + j; return isE1 ? gWc2[(20 + i) * 20 + c1] : 0.f; }
      return 0.f;
    }
  };
  auto v_o = [&](int k, int m, int nt) -> float {
    const int ks = k >> 5, j = k & 7, gk = (k >> 3) & 3;
    const int gm = m >> 2, r = m & 3;
    int kind = -1, c = 0;   // 0=pd, 1=cd0, 2=cd1
    if (nt == 0) {
      if (gm == 0) { kind = 0; c = r; }
      else if (gm == 1) { if (r < 2) { kind = 0; c = 4 + r; } else { kind = 1; c = r - 2; } }
      else if (gm == 2) { kind = 1; c = 2 + r; }
      else { kind = 2; c = r; }
    } else {
      if (gm == 0 && r < 2) { kind = 2; c = 4 + r; }
    }
    if (kind < 0) return 0.f;
    if (ks == 0) {
      if (j < 5) { const int i = 5 * gk + j; return (kind == 0) ? gWp3[i * 6 + c] : 0.f; }
      if (j < 7) { const int i = 5 * gk + (j - 5); return (kind == 2) ? gWc3[(20 + i) * 6 + c] : 0.f; }
      if (gk == 0) {
        if (kind == 0) return gbp3[c];
        if (kind == 1) return gbc3[c];
        return gbc3[6 + c];
      }
      return 0.f;
    } else {
      if (j < 5) { const int i = 5 * gk + j; return (kind == 1) ? gWc3[i * 6 + c] : 0.f; }
      const int i = 5 * gk + 2 + (j - 5);
      return (kind == 2) ? gWc3[(20 + i) * 6 + c] : 0.f;
    }
  };

  int ks, nt, which;
  if (fid < 4)       { ks = 0;                nt = fid;            which = 0; }
  else if (fid < 10) { int t = fid - 4;  ks = t / 3; nt = t % 3;   which = 1; }
  else if (fid < 20) { int t = fid - 10; ks = t / 5; nt = t % 5;   which = 2; }
  else if (fid < 24) { int t = fid - 20; ks = t / 2; nt = t % 2;   which = 3; }
  else if (fid < 30) { int t = fid - 24; ks = t / 3; nt = t % 3;   which = 4; }
  else               { int t = fid - 30; ks = t / 2; nt = t % 2;   which = 5; }

  FragU f;
#pragma unroll
  for (int j = 0; j < 8; ++j) {
    const int k = ks * 32 + g * 8 + j;
    float v;
    switch (which) {
      case 0: v = v_f1(k, c15, nt); break;
      case 1: v = v_f2(k, c15, nt); break;
      case 2: v = v_q(k, c15, nt); break;
      case 3: v = v_tp(k, c15, nt); break;
      case 4: v = v_cc(k, c15, nt); break;
      default: v = v_o(k, c15, nt); break;
    }
    f.b[j] = (__bf16)v;
  }
  ws[fid * 64 + lane] = f.q;
}

// ============================ MAIN KERNEL ============================
// Exact R7 structure (best: 36.3us) + s_setprio(1) around each chain's
// MFMA-dense body (T5: helps independent barrier-free waves, m191).
// Keep min-waves at 2 — higher values quantize the unified VGPR+AGPR
// budget down and spill (R5: min=4 -> 64 VGPR -> 247us).
__global__ __launch_bounds__(256, 2) void cdann_fwd(
    const float* __restrict__ gx, const int* __restrict__ gy,
    const u32x4* __restrict__ ws, float* __restrict__ gout)
{
  const int tid = (int)threadIdx.x;
  const int lane = tid & 63;
  const int w = tid >> 6;
  const int g = lane >> 4;
  const int c15 = lane & 15;

  // ---- prologue: 37 coalesced dwordx4 loads of prebuilt fragments ----
  FragU wF1[4], wF2[2][3], wQ[2][5], wTP[2][2], wCC[2][3], wO[2][2];
#pragma unroll
  for (int nt = 0; nt < 4; ++nt) wF1[nt].q = ws[nt * 64 + lane];
#pragma unroll
  for (int ks = 0; ks < 2; ++ks) {
#pragma unroll
    for (int nt = 0; nt < 3; ++nt) wF2[ks][nt].q = ws[(4 + ks * 3 + nt) * 64 + lane];
#pragma unroll
    for (int nt = 0; nt < 5; ++nt) wQ[ks][nt].q = ws[(10 + ks * 5 + nt) * 64 + lane];
#pragma unroll
    for (int nt = 0; nt < 2; ++nt) wTP[ks][nt].q = ws[(20 + ks * 2 + nt) * 64 + lane];
#pragma unroll
    for (int nt = 0; nt < 3; ++nt) wCC[ks][nt].q = ws[(24 + ks * 3 + nt) * 64 + lane];
#pragma unroll
    for (int nt = 0; nt < 2; ++nt) wO[ks][nt].q = ws[(30 + ks * 2 + nt) * 64 + lane];
  }
  f32x4 bF2[3];
#pragma unroll
  for (int nt = 0; nt < 3; ++nt) {
    BiasU b; b.q = ws[(34 + nt) * 64 + lane];
    bF2[nt] = b.f;
  }

  // ---- pin loop-invariants (anti-remat / anti-sink) ----
#pragma unroll
  for (int nt = 0; nt < 4; ++nt) asm volatile("" : "+v"(wF1[nt].u));
#pragma unroll
  for (int ks = 0; ks < 2; ++ks) {
#pragma unroll
    for (int nt = 0; nt < 3; ++nt) asm volatile("" : "+v"(wF2[ks][nt].u));
#pragma unroll
    for (int nt = 0; nt < 5; ++nt) asm volatile("" : "+v"(wQ[ks][nt].u));
#pragma unroll
    for (int nt = 0; nt < 2; ++nt) asm volatile("" : "+v"(wTP[ks][nt].u));
#pragma unroll
    for (int nt = 0; nt < 3; ++nt) asm volatile("" : "+v"(wCC[ks][nt].u));
#pragma unroll
    for (int nt = 0; nt < 2; ++nt) asm volatile("" : "+v"(wO[ks][nt].u));
  }
#pragma unroll
  for (int nt = 0; nt < 3; ++nt) asm volatile("" : "+v"(bF2[nt]));

  const f32x4 zf = {0.f, 0.f, 0.f, 0.f};
  const __bf16 one = (__bf16)1.0f;
  const __bf16 zero = (__bf16)0.0f;
  float* const outT = gout;
  float* const outP = gout + (size_t)2 * NBATCH;
  float* const outC = gout + (size_t)8 * NBATCH;

  // ---- per-chain pipeline: everything in registers ----
  auto chain = [&](const FragU& bx, int s, int y) {
    __builtin_amdgcn_s_setprio(1);
    // f1
    f32x4 aH[4];
#pragma unroll
    for (int nt = 0; nt < 4; ++nt) aH[nt] = MM(wF1[nt], bx, zf);
    FragU bh0, bh1;
#pragma unroll
    for (int j = 0; j < 8; ++j) {
      bh0.b[j] = (__bf16)fmaxf(aH[j >> 2][j & 3], 0.f);
      bh1.b[j] = (__bf16)fmaxf(aH[2 + (j >> 2)][j & 3], 0.f);
    }
    // f2
    f32x4 aF[3];
#pragma unroll
    for (int nt = 0; nt < 3; ++nt) aF[nt] = MM(wF2[1][nt], bh1, MM(wF2[0][nt], bh0, zf));
    FragU bf0, bf1;
#pragma unroll
    for (int j = 0; j < 8; ++j)
      bf0.b[j] = (__bf16)fmaxf(aF[j >> 2][j & 3] + bF2[j >> 2][j & 3], 0.f);
#pragma unroll
    for (int j = 0; j < 4; ++j)
      bf1.b[j] = (__bf16)fmaxf(aF[2][j] + bF2[2][j], 0.f);
    bf1.b[4] = (g == 0) ? one : zero;   // v=36: const1 (head-bias row)
    bf1.b[5] = zero; bf1.b[6] = zero; bf1.b[7] = zero;
    // quad heads
    f32x4 aQ[5];
#pragma unroll
    for (int nt = 0; nt < 5; ++nt) aQ[nt] = MM(wQ[1][nt], bf1, MM(wQ[0][nt], bf0, zf));
    auto rq = [&](int u) { return (__bf16)fmaxf(aQ[u >> 2][u & 3], 0.f); };
    FragU tp0, tp1, cc0, cc1;
#pragma unroll
    for (int j = 0; j < 5; ++j) {
      tp0.b[j] = rq(j);
      tp1.b[j] = rq(5 + j);
      cc0.b[j] = rq(10 + j);
      cc1.b[j] = rq(15 + j);
    }
    tp0.b[5] = zero; tp0.b[6] = zero; tp0.b[7] = (g == 0) ? one : zero;
    tp1.b[5] = zero; tp1.b[6] = zero; tp1.b[7] = zero;
    cc0.b[5] = zero; cc0.b[6] = zero; cc0.b[7] = (g == 0) ? one : zero;
    cc1.b[5] = zero; cc1.b[6] = zero; cc1.b[7] = zero;
    // [t2|p2] and [c2e0|c2e1]
    f32x4 aT[2], aC[3];
#pragma unroll
    for (int nt = 0; nt < 2; ++nt) aT[nt] = MM(wTP[1][nt], tp1, MM(wTP[0][nt], tp0, zf));
#pragma unroll
    for (int nt = 0; nt < 3; ++nt) aC[nt] = MM(wCC[1][nt], cc1, MM(wCC[0][nt], cc0, zf));
    // final B-frag [p2;c2e0;c2e1]+const
    FragU f50, f51;
#pragma unroll
    for (int j = 0; j < 4; ++j) {
      f50.b[j] = (__bf16)fmaxf(aT[0][j], 0.f);
      f51.b[j] = (__bf16)fmaxf(aC[0][j], 0.f);
    }
    f50.b[4] = (__bf16)fmaxf(aT[1][0], 0.f);
    f50.b[5] = (__bf16)fmaxf(aC[1][1], 0.f);
    f50.b[6] = (__bf16)fmaxf(aC[1][2], 0.f);
    f50.b[7] = (g == 0) ? one : zero;
    f51.b[4] = (__bf16)fmaxf(aC[1][0], 0.f);
    f51.b[5] = (__bf16)fmaxf(aC[1][3], 0.f);
    f51.b[6] = (__bf16)fmaxf(aC[2][0], 0.f);
    f51.b[7] = (__bf16)fmaxf(aC[2][1], 0.f);
    // [pd|cd0|cd1]
    f32x4 aO[2];
#pragma unroll
    for (int nt = 0; nt < 2; ++nt) aO[nt] = MM(wO[1][nt], f51, MM(wO[0][nt], f50, zf));
    __builtin_amdgcn_s_setprio(0);
    // stores (raw logits)
    if (g == 0) {
      f32x2 t2v = {aT[1][1], aT[1][2]};
      *(f32x2*)(outT + (size_t)s * 2) = t2v;
      f32x2 pa = {aO[0][0], aO[0][1]}, pb = {aO[0][2], aO[0][3]};
      *(f32x2*)(outP + (size_t)s * 6) = pa;
      *(f32x2*)(outP + (size_t)s * 6 + 2) = pb;
      if (y) { f32x2 cv = {aO[1][0], aO[1][1]}; *(f32x2*)(outC + (size_t)s * 6 + 4) = cv; }
    } else if (g == 1) {
      f32x2 pc = {aO[0][0], aO[0][1]};
      *(f32x2*)(outP + (size_t)s * 6 + 4) = pc;
      if (!y) { f32x2 cv = {aO[0][2], aO[0][3]}; *(f32x2*)(outC + (size_t)s * 6) = cv; }
    } else if (g == 2) {
      if (!y) {
        f32x2 ca = {aO[0][0], aO[0][1]}, cb = {aO[0][2], aO[0][3]};
        *(f32x2*)(outC + (size_t)s * 6 + 2) = ca;
        *(f32x2*)(outC + (size_t)s * 6 + 4) = cb;
      }
    } else {
      if (y) {
        f32x2 ca = {aO[0][0], aO[0][1]}, cb = {aO[0][2], aO[0][3]};
        *(f32x2*)(outC + (size_t)s * 6) = ca;
        *(f32x2*)(outC + (size_t)s * 6 + 2) = cb;
      }
    }
  };

  // ---- x/y prefetch: lane (g,c15) reads x[s][g*8..g*8+7]; chains A(+0), B(+64) ----
  float xrA[8], xrB[8];
  int yA, yB;
  auto loadx = [&](int it) {
    const int sA = it * 128 + w * 16 + c15;
    const float* xpA = gx + (size_t)sA * 30 + g * 8;
    const float* xpB = xpA + (size_t)64 * 30;
    if (g < 3) {
      F4u a0 = *(const F4u*)xpA; F4u a1 = *(const F4u*)(xpA + 4);
      F4u b0 = *(const F4u*)xpB; F4u b1 = *(const F4u*)(xpB + 4);
#pragma unroll
      for (int j = 0; j < 4; ++j) {
        xrA[j] = a0.v[j]; xrA[4 + j] = a1.v[j];
        xrB[j] = b0.v[j]; xrB[4 + j] = b1.v[j];
      }
    } else {
      F4u a0 = *(const F4u*)xpA; F2u a1 = *(const F2u*)(xpA + 4);
      F4u b0 = *(const F4u*)xpB; F2u b1 = *(const F2u*)(xpB + 4);
#pragma unroll
      for (int j = 0; j < 4; ++j) { xrA[j] = a0.v[j]; xrB[j] = b0.v[j]; }
      xrA[4] = a1.v[0]; xrA[5] = a1.v[1]; xrA[6] = 1.0f; xrA[7] = 0.0f;
      xrB[4] = b1.v[0]; xrB[5] = b1.v[1]; xrB[6] = 1.0f; xrB[7] = 0.0f;
    }
    yA = gy[sA]; yB = gy[sA + 64];
  };

  int it = (int)blockIdx.x;
  loadx(it);

  while (it < NTIL) {
    const int nit = it + GRID;
    const int sgA = it * 128 + w * 16 + c15;
    const int sgB = sgA + 64;
    const int ysA = yA, ysB = yB;

    FragU bxA, bxB;
#pragma unroll
    for (int j = 0; j < 8; ++j) { bxA.b[j] = (__bf16)xrA[j]; bxB.b[j] = (__bf16)xrB[j]; }

    if (nit < NTIL) loadx(nit);   // next tile's loads fly under the chains

    chain(bxA, sgA, ysA);
    chain(bxB, sgB, ysB);

    it = nit;
  }
}

extern "C" void kernel_launch(void* const* d_in, const int* in_sizes, int n_in,
                              void* d_out, int out_size, void* d_ws, size_t ws_size,
                              hipStream_t stream) {
  (void)in_sizes; (void)n_in; (void)ws_size; (void)out_size;
  const float* gx  = (const float*)d_in[0];
  const int*   gy  = (const int*)d_in[1];
  const float* Wf1 = (const float*)d_in[2];  const float* bf1 = (const float*)d_in[3];
  const float* Wf2 = (const float*)d_in[4];  const float* bf2 = (const float*)d_in[5];
  const float* Wt1 = (const float*)d_in[6];  const float* bt1 = (const float*)d_in[7];
  const float* Wt2 = (const float*)d_in[8];  const float* bt2 = (const float*)d_in[9];
  const float* Wp1 = (const float*)d_in[10]; const float* bp1 = (const float*)d_in[11];
  const float* Wp2 = (const float*)d_in[12]; const float* bp2 = (const float*)d_in[13];
  const float* Wp3 = (const float*)d_in[14]; const float* bp3 = (const float*)d_in[15];
  const float* Wc1 = (const float*)d_in[16]; const float* bc1 = (const float*)d_in[17];
  const float* Wc2 = (const float*)d_in[18]; const float* bc2 = (const float*)d_in[19];
  const float* Wc3 = (const float*)d_in[20]; const float* bc3 = (const float*)d_in[21];
  float* out = (float*)d_out;
  u32x4* ws = (u32x4*)d_ws;

  cdann_prep<<<dim3(NFRAG), dim3(64), 0, stream>>>(
      Wf1, bf1, Wf2, bf2, Wt1, bt1, Wt2, bt2,
      Wp1, bp1, Wp2, bp2, Wp3, bp3, Wc1, bc1, Wc2, bc2, Wc3, bc3, ws);

  cdann_fwd<<<dim3(GRID), dim3(256), 0, stream>>>(gx, gy, ws, out);
}